// Round 2
// baseline (498778.369 us; speedup 1.0000x reference)
//
#include <hip/hip_runtime.h>
#include <hip/hip_bf16.h>

// TrainerRNN: 10-layer GRU (T=2048, IN=384, H=768) + linear head (384).
// ROUND 1: all tensors are fp32 (reference dtypes; R0's bf16 guess produced
// NaN — fp32 mantissa bits read as bf16 hit exponent-0xFF patterns).
//  - Persistent kernel: 256 blocks x 192 thr (3 waves). Wave owns 1 hidden
//    unit; its 6 weight rows (r,z,n x ih,hh) live fp32 in LDS (54 KB/block).
//  - Sequential layers; per-timestep device barrier (single counter,
//    release/acquire, monotone target -> no reset races). 20480 barriers.
//  - Co-residency: grid=256=#CUs, <=2 blocks/CU fit by LDS -> capacity 512,
//    all 256 resident -> no deadlock (R0 confirmed: ran, no hang).
//  - FC head: separate kernel, one block per timestep.

#define T_SEQ 2048
#define H_DIM 768
#define IN0   384
#define G3    2304      // 3*H
#define NLAYER 10
#define NBLK  256
#define NTHR  192       // 3 waves, one per owned hidden unit
#define NOUT  384

__device__ __forceinline__ float sigm(float x) { return 1.0f / (1.0f + __expf(-x)); }

extern "C" __global__ __launch_bounds__(NTHR, 1) void gru_persistent(
    const float* __restrict__ x,
    const float* __restrict__ wih0,
    const float* __restrict__ whh0,
    const float* __restrict__ bih0,
    const float* __restrict__ bhh0,
    const float* __restrict__ wihS,
    const float* __restrict__ whhS,
    const float* __restrict__ bihS,
    const float* __restrict__ bhhS,
    float* __restrict__ buf0, float* __restrict__ buf1,
    unsigned int* __restrict__ ctr)
{
    __shared__ float lds[3 * 6 * H_DIM];   // 3 units * 4608 floats = 54 KB

    const int tid  = threadIdx.x;
    const int lane = tid & 63;
    const int wv   = tid >> 6;             // 0..2
    const int bid  = blockIdx.x;
    const int j    = bid * 3 + wv;         // owned hidden unit, 0..767
    unsigned int gstep = 0;

    for (int l = 0; l < NLAYER; ++l) {
        const int Din = (l == 0) ? IN0 : H_DIM;
        const float* wih = (l == 0) ? wih0 : wihS + (size_t)(l - 1) * G3 * H_DIM;
        const float* whh = (l == 0) ? whh0 : whhS + (size_t)(l - 1) * G3 * H_DIM;
        const float* bih = (l == 0) ? bih0 : bihS + (size_t)(l - 1) * G3;
        const float* bhh = (l == 0) ? bhh0 : bhhS + (size_t)(l - 1) * G3;
        const float* yp = (l & 1) ? buf0 : buf1;   // prev layer output (l>0)
        float*       yc = (l & 1) ? buf1 : buf0;   // this layer's output

        // ---- stage this wave's 6 weight rows into LDS (float4 loads) ----
        const int ustride = 3 * Din + 3 * H_DIM;
        float* L = lds + wv * ustride;
        for (int g = 0; g < 3; ++g) {
            const float4* src = (const float4*)(wih + (size_t)(j + g * H_DIM) * Din);
            float4* dst = (float4*)(L + g * Din);
            for (int k = lane; k < Din / 4; k += 64) dst[k] = src[k];
        }
        for (int g = 0; g < 3; ++g) {
            const float4* src = (const float4*)(whh + (size_t)(j + g * H_DIM) * H_DIM);
            float4* dst = (float4*)(L + 3 * Din + g * H_DIM);
            for (int k = lane; k < H_DIM / 4; k += 64) dst[k] = src[k];
        }
        const float bir = bih[j], biz = bih[j + 768], bin_ = bih[j + 1536];
        const float bhr = bhh[j], bhz = bhh[j + 768], bhn  = bhh[j + 1536];
        __syncthreads();

        const float* Lihr = L;
        const float* Lihz = L + Din;
        const float* Lihn = L + 2 * Din;
        const float* Lhr  = L + 3 * Din;
        const float* Lhz  = Lhr + H_DIM;
        const float* Lhn  = Lhz + H_DIM;

        for (int t = 0; t < T_SEQ; ++t) {
            float air = 0.f, aiz = 0.f, ain = 0.f, ahr = 0.f, ahz = 0.f, ahn = 0.f;

            // input projection (fused gi)
            if (l == 0) {
                const float* xr = x + (size_t)t * IN0;
#pragma unroll
                for (int kk = 0; kk < IN0 / 64; ++kk) {
                    const int k = lane + kk * 64;
                    const float xv = xr[k];
                    air += xv * Lihr[k]; aiz += xv * Lihz[k]; ain += xv * Lihn[k];
                }
            } else {
                const float* xr = yp + (size_t)t * H_DIM;
#pragma unroll
                for (int kk = 0; kk < H_DIM / 64; ++kk) {
                    const int k = lane + kk * 64;
                    const float xv = xr[k];
                    air += xv * Lihr[k]; aiz += xv * Lihz[k]; ain += xv * Lihn[k];
                }
            }

            // hidden projection
            float hprev = 0.f;
            if (t > 0) {
                const float* hr = yc + (size_t)(t - 1) * H_DIM;
                hprev = hr[j];
#pragma unroll
                for (int kk = 0; kk < H_DIM / 64; ++kk) {
                    const int k = lane + kk * 64;
                    const float hv = hr[k];
                    ahr += hv * Lhr[k]; ahz += hv * Lhz[k]; ahn += hv * Lhn[k];
                }
            }

            // 64-lane butterfly reduce, 6 accumulators
#pragma unroll
            for (int off = 32; off > 0; off >>= 1) {
                air += __shfl_xor(air, off, 64);
                aiz += __shfl_xor(aiz, off, 64);
                ain += __shfl_xor(ain, off, 64);
                ahr += __shfl_xor(ahr, off, 64);
                ahz += __shfl_xor(ahz, off, 64);
                ahn += __shfl_xor(ahn, off, 64);
            }

            if (lane == 0) {
                const float r = sigm(air + bir + ahr + bhr);
                const float z = sigm(aiz + biz + ahz + bhz);
                const float n = tanhf(ain + bin_ + r * (ahn + bhn));
                yc[(size_t)t * H_DIM + j] = (1.f - z) * n + z * hprev;
            }

            // ---- device-wide step barrier ----
            __threadfence();
            __syncthreads();
            ++gstep;
            if (tid == 0) {
                __hip_atomic_fetch_add(ctr, 1u, __ATOMIC_RELEASE, __HIP_MEMORY_SCOPE_AGENT);
                const unsigned int target = (unsigned int)NBLK * gstep;
                while (__hip_atomic_load(ctr, __ATOMIC_ACQUIRE, __HIP_MEMORY_SCOPE_AGENT) < target)
                    __builtin_amdgcn_s_sleep(1);
            }
            __syncthreads();
        }
    }
}

extern "C" __global__ __launch_bounds__(NOUT, 1) void fc_head(
    const float* __restrict__ h,
    const float* __restrict__ fw,
    const float* __restrict__ fb,
    float* __restrict__ out)
{
    __shared__ float hs[H_DIM];
    const int t = blockIdx.x;
    const float* hr = h + (size_t)t * H_DIM;
    for (int k = threadIdx.x; k < H_DIM; k += NOUT) hs[k] = hr[k];
    __syncthreads();

    const int o = threadIdx.x;
    float acc = fb[o];
    const float* wr = fw + (size_t)o * H_DIM;
#pragma unroll 8
    for (int k = 0; k < H_DIM; ++k) acc += hs[k] * wr[k];
    out[(size_t)t * NOUT + o] = acc;
}

extern "C" void kernel_launch(void* const* d_in, const int* in_sizes, int n_in,
                              void* d_out, int out_size, void* d_ws, size_t ws_size,
                              hipStream_t stream)
{
    const float* x    = (const float*)d_in[0];
    const float* wih0 = (const float*)d_in[1];
    const float* whh0 = (const float*)d_in[2];
    const float* bih0 = (const float*)d_in[3];
    const float* bhh0 = (const float*)d_in[4];
    const float* wihS = (const float*)d_in[5];
    const float* whhS = (const float*)d_in[6];
    const float* bihS = (const float*)d_in[7];
    const float* bhhS = (const float*)d_in[8];
    const float* fcw  = (const float*)d_in[9];
    const float* fcb  = (const float*)d_in[10];

    char* ws = (char*)d_ws;
    unsigned int* ctr = (unsigned int*)ws;                       // barrier counter
    float* buf0 = (float*)(ws + 256);                            // [2048,768] fp32
    float* buf1 = buf0 + (size_t)T_SEQ * H_DIM;                  // [2048,768] fp32

    hipMemsetAsync(ctr, 0, 256, stream);                         // zero barrier state

    hipLaunchKernelGGL(gru_persistent, dim3(NBLK), dim3(NTHR), 0, stream,
                       x, wih0, whh0, bih0, bhh0, wihS, whhS, bihS, bhhS,
                       buf0, buf1, ctr);

    // layer 9 (odd) wrote buf1
    hipLaunchKernelGGL(fc_head, dim3(T_SEQ), dim3(NOUT), 0, stream,
                       buf1, fcw, fcb, (float*)d_out);
}